// Round 18
// baseline (278.035 us; speedup 1.0000x reference)
//
#include <hip/hip_runtime.h>

#define N 2048
#define LEV 256
#define KS 16

typedef __attribute__((ext_vector_type(8))) short bfx8;
typedef __attribute__((ext_vector_type(4))) float fx4;
typedef unsigned short u16;
typedef unsigned int u32;

static const size_t NN = (size_t)N * N;

__device__ inline u16 bf16_rne(float f) {
    u32 u = __builtin_bit_cast(u32, f);
    u32 r = (u + 0x7FFFu + ((u >> 16) & 1u)) >> 16;
    return (u16)r;
}
__device__ inline float bf16_f(u16 h) {
    u32 u = ((u32)h) << 16;
    return __builtin_bit_cast(float, u);
}

// async global->LDS, 16B per lane. LDS dest = wave-uniform base + lane*16.
#define GLDS16(gp, lp) __builtin_amdgcn_global_load_lds( \
    (const __attribute__((address_space(1))) void*)(uintptr_t)(gp), \
    (__attribute__((address_space(3))) void*)(u32)(uintptr_t)(lp), 16, 0, 0)

// sum over the 4 lanes of each quad (lane^1 then lane^2), VALU-only via DPP.
__device__ inline float qadd(float x) {
#if __has_builtin(__builtin_amdgcn_mov_dpp)
    int a = __builtin_amdgcn_mov_dpp(__builtin_bit_cast(int, x), 0xB1, 0xF, 0xF, true);
    float y = x + __builtin_bit_cast(float, a);
    int b = __builtin_amdgcn_mov_dpp(__builtin_bit_cast(int, y), 0x4E, 0xF, 0xF, true);
    return y + __builtin_bit_cast(float, b);
#else
    float y = x + __shfl_xor(x, 1);
    return y + __shfl_xor(y, 2);
#endif
}

// ---------------------------------------------------------------------------
// flags[l] = (sel[l] ∩ sel[l-1] != ∅): does level l's gather set collide with
// level l-1's write set? Precomputed so front_k can issue gathers one level
// ahead (off-chain) and re-gather only on flagged (~12%) levels.
// ---------------------------------------------------------------------------
__global__ __launch_bounds__(256)
void flags_k(const int* __restrict__ sel, int* __restrict__ flags) {
    const int l = threadIdx.x;
    int f = 0;
    if (l > 0) {
        int a[KS], b[KS];
        #pragma unroll
        for (int k = 0; k < KS; ++k) { a[k] = sel[l * KS + k]; b[k] = sel[(l - 1) * KS + k]; }
        #pragma unroll
        for (int i = 0; i < KS; ++i)
            #pragma unroll
            for (int j = 0; j < KS; ++j)
                f |= (a[i] == b[j]);
    }
    flags[l] = f;
}

// ---------------------------------------------------------------------------
// FUSED front. Blocks [0,2048): build RT column with COLLISION-PRECOMPUTED
// LOOKAHEAD — level l+1's gathers issue BEFORE level l's write (stale-legal);
// flagged levels (sel-overlap with previous write set) re-gather fresh.
// Non-flagged chain: dot + quad-DPP only (no LDS write->read round trip).
// DS program order (single wave) gives: write(l-1) < gathers(l+1) < write(l).
// Emits RT fp32 + RT2 split planes. Blocks [2048,+8192): stream-split A.
// ---------------------------------------------------------------------------
__global__ __launch_bounds__(64)
void front_k(const float* __restrict__ O_all, const int* __restrict__ sel,
             const int* __restrict__ flags,
             float* __restrict__ RT, u16* __restrict__ rth,
             const float* __restrict__ A, u16* __restrict__ a2h) {
    __shared__ float x[2048];
    const int lane = threadIdx.x;

    if (blockIdx.x >= 2048) {           // ---- A-split path ----
        u16* a2l = a2h + NN;
        size_t p = (((size_t)blockIdx.x - 2048) * 64 + lane) * 8;
        float4 v0 = *(const float4*)(A + p);
        float4 v1 = *(const float4*)(A + p + 4);
        float vv[8] = {v0.x, v0.y, v0.z, v0.w, v1.x, v1.y, v1.z, v1.w};
        bfx8 hs, ls;
        #pragma unroll
        for (int i = 0; i < 8; ++i) {
            u16 h = bf16_rne(vv[i]);
            hs[i] = (short)h;
            ls[i] = (short)bf16_rne(vv[i] - bf16_f(h));
        }
        *(bfx8*)(a2h + p) = hs;
        *(bfx8*)(a2l + p) = ls;
        return;
    }

    // ---- build-right path ----
    const int i    = lane >> 2;     // row 0..15
    const int kg   = lane & 3;      // k-quarter 0..3
    const int col  = blockIdx.x;

    const float4 z = make_float4(0.f, 0.f, 0.f, 0.f);
    #pragma unroll
    for (int q = 0; q < 8; ++q) *(float4*)&x[q * 256 + lane * 4] = z;
    if (lane == 0) x[col] = 1.0f;   // e_col; in-order DS, same wave

    const float* obase = O_all + i * KS + kg * 4;
    const int*   gbase = sel + kg * 4;

    float4 o_c = *(const float4*)(obase);           // level 0
    int4   g_c = *(const int4*)(gbase);
    int    w_c = sel[i];
    int    fl_c = 0;                                // level 0 reads init state
    float4 o_n = *(const float4*)(obase + 256);     // level 1
    int4   g_n = *(const int4*)(gbase + KS);
    int    w_n = sel[KS + i];
    int    fl_n = flags[1];

    // initial gathers for level 0 (after init writes; program order)
    float gv0 = x[g_c.x], gv1 = x[g_c.y], gv2 = x[g_c.z], gv3 = x[g_c.w];

    for (int l = 0; l < LEV; ++l) {
        // prefetch level l+2 (off critical path)
        float4 o_p; int4 g_p; int w_p, fl_p;
        if (l + 2 < LEV) {
            o_p  = *(const float4*)(obase + (size_t)(l + 2) * 256);
            g_p  = *(const int4*)(gbase + (l + 2) * KS);
            w_p  = sel[(l + 2) * KS + i];
            fl_p = flags[l + 2];
        } else { o_p = o_n; g_p = g_n; w_p = w_n; fl_p = 0; }

        // values for level l: lookahead gathers, or fresh re-gather if the
        // gather set collided with level l-1's write set (wave-uniform branch)
        float v0, v1, v2, v3;
        if (fl_c) {
            v0 = x[g_c.x]; v1 = x[g_c.y]; v2 = x[g_c.z]; v3 = x[g_c.w];
        } else {
            v0 = gv0; v1 = gv1; v2 = gv2; v3 = gv3;
        }

        // gathers for level l+1 (BEFORE write l; staleness covered by fl_n)
        float n0 = x[g_n.x], n1 = x[g_n.y], n2 = x[g_n.z], n3 = x[g_n.w];

        // compute level l
        float p = o_c.x * v0 + o_c.y * v1 + o_c.z * v2 + o_c.w * v3;
        p = qadd(p);
        if (kg == 0) x[w_c] = p;

        // rotate
        gv0 = n0; gv1 = n1; gv2 = n2; gv3 = n3;
        o_c = o_n; g_c = g_n; w_c = w_n; fl_c = fl_n;
        o_n = o_p; g_n = g_p; w_n = w_p; fl_n = fl_p;
    }

    // epilogue: RT fp32 + RT2 split planes (coalesced row-major writes)
    u16* rtl = rth + NN;
    #pragma unroll
    for (int q = 0; q < 8; ++q) {
        float4 v = *(const float4*)&x[q * 256 + lane * 4];
        *(float4*)&RT[(size_t)col * N + q * 256 + lane * 4] = v;
        float vv[4] = {v.x, v.y, v.z, v.w};
        u16 hh[4], ll[4];
        #pragma unroll
        for (int e = 0; e < 4; ++e) {
            hh[e] = bf16_rne(vv[e]);
            ll[e] = bf16_rne(vv[e] - bf16_f(hh[e]));
        }
        const size_t po = (size_t)col * N + q * 256 + lane * 4;
        *(ushort4*)(rth + po) = make_ushort4(hh[0], hh[1], hh[2], hh[3]);
        *(ushort4*)(rtl + po) = make_ushort4(ll[0], ll[1], ll[2], ll[3]);
    }
}

// ---------------------------------------------------------------------------
// From RT (= R^T row-major): R2 = split(R) + Rrm (R fp32). RT2 already
// written by front_k. 64x64 LDS transpose tiles.
// ---------------------------------------------------------------------------
__global__ __launch_bounds__(256)
void split_rt_k(const float* __restrict__ RT, u16* __restrict__ r2h,
                float* __restrict__ Rrm) {
    __shared__ float t[64][65];
    u16* r2l = r2h + NN;
    const int r0 = (blockIdx.x >> 5) * 64, c0 = (blockIdx.x & 31) * 64;
    #pragma unroll
    for (int i = 0; i < 16; ++i) {
        int q = i * 256 + threadIdx.x;
        int rr = q >> 6, cc = q & 63;
        t[rr][cc] = RT[(size_t)(r0 + rr) * N + c0 + cc];
    }
    __syncthreads();
    #pragma unroll
    for (int i = 0; i < 16; ++i) {
        int q = i * 256 + threadIdx.x;
        int rr = q >> 6, cc = q & 63;
        float w = t[cc][rr];                        // = R[c0+rr][r0+cc]
        u16 h2 = bf16_rne(w);
        size_t pt = (size_t)(c0 + rr) * N + r0 + cc;
        r2h[pt] = h2;                               // split(R)
        r2l[pt] = bf16_rne(w - bf16_f(h2));
        Rrm[pt] = w;                                // R fp32 (output slot)
    }
}

// ---------------------------------------------------------------------------
// D fp32 = hi + lo
// ---------------------------------------------------------------------------
__global__ __launch_bounds__(256)
void unsplit_k(const u16* __restrict__ hi, float* __restrict__ dst) {
    const u16* lo = hi + NN;
    size_t p = ((size_t)blockIdx.x * 256 + threadIdx.x) * 8;
    bfx8 hs = *(const bfx8*)(hi + p);
    bfx8 ls = *(const bfx8*)(lo + p);
    float4 o0, o1;
    o0.x = bf16_f((u16)hs[0]) + bf16_f((u16)ls[0]);
    o0.y = bf16_f((u16)hs[1]) + bf16_f((u16)ls[1]);
    o0.z = bf16_f((u16)hs[2]) + bf16_f((u16)ls[2]);
    o0.w = bf16_f((u16)hs[3]) + bf16_f((u16)ls[3]);
    o1.x = bf16_f((u16)hs[4]) + bf16_f((u16)ls[4]);
    o1.y = bf16_f((u16)hs[5]) + bf16_f((u16)ls[5]);
    o1.z = bf16_f((u16)hs[6]) + bf16_f((u16)ls[6]);
    o1.w = bf16_f((u16)hs[7]) + bf16_f((u16)ls[7]);
    *(float4*)(dst + p)     = o0;
    *(float4*)(dst + p + 4) = o1;
}

// ---------------------------------------------------------------------------
// C = X * Y^T via 3-term bf16 split MFMA. R13-PROVEN: 128x64 tile, BK=64,
// single-buffered X+Y LDS via global_load_lds (48 KB) -> grid 512 = 2
// blocks/CU co-resident. Both-sides XOR swizzle; XCD super-tile swizzle.
// ---------------------------------------------------------------------------
template<int MASKED, int OMODE>
__global__ __launch_bounds__(256)
void gemm_bf3(const u16* __restrict__ Xp, const u16* __restrict__ Yp,
              float* __restrict__ Cf, u16* __restrict__ Cs,
              const int* __restrict__ wav, int Lw) {
    // planes: Xh[128*64] @0, Xl @16384, Yh[64*64] @32768, Yl @40960 (bytes)
    __shared__ __align__(16) u16 sm[24576];        // 48 KB single buffer
    __shared__ float rowf[128], colf[64];

    const int tid = threadIdx.x;
    const int xcd = blockIdx.x & 7, idx = blockIdx.x >> 3;   // idx 0..63
    const int sup = 4 * xcd + (idx >> 4);                    // 0..31
    const int wi4 = idx & 15;
    const int by = (sup >> 3) * 4 + (wi4 >> 2);              // 0..15
    const int bx = (sup & 7) * 4 + (wi4 & 3);                // 0..31
    const int i0 = by * 128, j0 = bx * 64;
    const int lane = tid & 63, w = tid >> 6;
    const int wm = (w >> 1) * 64, wn = (w & 1) * 32;
    const int fr = lane & 15;

    if (MASKED) {
        if (tid < 128) rowf[tid] = 1.0f;
        if (tid >= 128 && tid < 192) colf[tid - 128] = 1.0f;
        __syncthreads();
        for (int t = tid; t < Lw; t += 256) {
            int wv = wav[t];
            int dr = wv - i0; if (0 <= dr && dr < 128) rowf[dr] = 0.0f;
            int dc = wv - j0; if (0 <= dc && dc < 64)  colf[dc] = 0.0f;
        }
    }

    fx4 acc[4][2];
    #pragma unroll
    for (int m = 0; m < 4; ++m)
        #pragma unroll
        for (int n = 0; n < 2; ++n)
            acc[m][n] = (fx4)0.0f;

    const u16* Xh = Xp; const u16* Xl = Xp + NN;
    const u16* Yh = Yp; const u16* Yl = Yp + NN;

    const int rl   = lane >> 3;
    const int gcol = ((lane & 7) ^ rl) << 3;
    const int wq   = w * 1024;

    #define STAGE(kt) { \
        const int k0s = (kt) * 64; \
        char* lb0 = (char*)sm + wq; \
        _Pragma("unroll") \
        for (int q = 0; q < 4; ++q) { \
            const int row = q * 32 + w * 8 + rl; \
            const size_t xo = (size_t)(i0 + row) * N + k0s + gcol; \
            GLDS16(Xh + xo, lb0 + q * 4096); \
            GLDS16(Xl + xo, lb0 + 16384 + q * 4096); \
        } \
        _Pragma("unroll") \
        for (int q = 0; q < 2; ++q) { \
            const int row = q * 32 + w * 8 + rl; \
            const size_t yo = (size_t)(j0 + row) * N + k0s + gcol; \
            GLDS16(Yh + yo, lb0 + 32768 + q * 4096); \
            GLDS16(Yl + yo, lb0 + 40960 + q * 4096); \
        } }

    const int kq  = (lane >> 4) << 4;
    const int frx = (fr & 7) << 4;

    #define COMPUTE() { \
        const char* base = (const char*)sm; \
        _Pragma("unroll") \
        for (int s = 0; s < 2; ++s) { \
            const int cb = s * 64 + kq; \
            bfx8 ah[4], al[4]; \
            _Pragma("unroll") \
            for (int m = 0; m < 4; ++m) { \
                const int off = (wm + m * 16 + fr) * 128 + (cb ^ frx); \
                ah[m] = *(const bfx8*)(base + off); \
                al[m] = *(const bfx8*)(base + 16384 + off); \
            } \
            _Pragma("unroll") \
            for (int n = 0; n < 2; ++n) { \
                const int off = (wn + n * 16 + fr) * 128 + (cb ^ frx); \
                bfx8 bh = *(const bfx8*)(base + 32768 + off); \
                bfx8 bl = *(const bfx8*)(base + 40960 + off); \
                _Pragma("unroll") \
                for (int m = 0; m < 4; ++m) { \
                    acc[m][n] = __builtin_amdgcn_mfma_f32_16x16x32_bf16(ah[m], bh, acc[m][n], 0, 0, 0); \
                    acc[m][n] = __builtin_amdgcn_mfma_f32_16x16x32_bf16(ah[m], bl, acc[m][n], 0, 0, 0); \
                    acc[m][n] = __builtin_amdgcn_mfma_f32_16x16x32_bf16(al[m], bh, acc[m][n], 0, 0, 0); \
                } \
            } \
        } }

    constexpr int NT = N / 64;
    for (int kt = 0; kt < NT; ++kt) {
        STAGE(kt)
        __syncthreads();
        COMPUTE()
        __syncthreads();
    }

    const int crow0 = (lane >> 4) * 4;
    #pragma unroll
    for (int m = 0; m < 4; ++m) {
        #pragma unroll
        for (int n = 0; n < 2; ++n) {
            #pragma unroll
            for (int r = 0; r < 4; ++r) {
                const int li = wm + m * 16 + crow0 + r;
                const int lj = wn + n * 16 + fr;
                float v = acc[m][n][r];
                if (MASKED) {
                    if (i0 + li != j0 + lj) v *= rowf[li] * colf[lj];
                }
                const size_t off = (size_t)(i0 + li) * N + j0 + lj;
                if (OMODE == 0) {
                    Cf[off] = v;
                } else {
                    u16 h = bf16_rne(v);
                    Cs[off]      = h;
                    Cs[NN + off] = bf16_rne(v - bf16_f(h));
                }
            }
        }
    }
    #undef STAGE
    #undef COMPUTE
}

// ---------------------------------------------------------------------------
// SYMMETRIC-output GEMM (R17-proven): 64x64 tiles, 528 upper-tri blocks
// (>= 2 blocks/CU). Off-diag blocks mirror via LDS bounce; diag blocks
// self-contained. Single-writer everywhere.
// ---------------------------------------------------------------------------
template<int MASKED, int OMODE>
__global__ __launch_bounds__(256)
void gemm_sym(const u16* __restrict__ Xp, const u16* __restrict__ Yp,
              float* __restrict__ Cf, u16* __restrict__ Cs,
              const int* __restrict__ wav, int Lw) {
    // planes: Xh[64*64] @0, Xl @8192, Yh @16384, Yl @24576 (bytes)
    __shared__ __align__(16) u16 sm[16384];        // 32 KB; epilogue Ct reuse
    __shared__ float rowf[64], colf[64];

    const int tid = threadIdx.x;
    int swz = (blockIdx.x & 7) * 66 + (blockIdx.x >> 3);
    int t = swz, by = 0;
    #pragma unroll 1
    while (t >= 32 - by) { t -= 32 - by; ++by; }
    const int bx = by + t;                          // by <= bx < 32
    const int i0 = by * 64, j0 = bx * 64;
    const int lane = tid & 63, w = tid >> 6;
    const int wm = (w >> 1) * 32, wn = (w & 1) * 32;
    const int fr = lane & 15;

    if (MASKED) {
        if (tid < 64) rowf[tid] = 1.0f;
        if (tid >= 128 && tid < 192) colf[tid - 128] = 1.0f;
        __syncthreads();
        for (int t2 = tid; t2 < Lw; t2 += 256) {
            int wv = wav[t2];
            int dr = wv - i0; if (0 <= dr && dr < 64) rowf[dr] = 0.0f;
            int dc = wv - j0; if (0 <= dc && dc < 64) colf[dc] = 0.0f;
        }
    }

    fx4 acc[2][2];
    #pragma unroll
    for (int m = 0; m < 2; ++m)
        #pragma unroll
        for (int n = 0; n < 2; ++n)
            acc[m][n] = (fx4)0.0f;

    const u16* Xh = Xp; const u16* Xl = Xp + NN;
    const u16* Yh = Yp; const u16* Yl = Yp + NN;

    const int rl   = lane >> 3;
    const int gcol = ((lane & 7) ^ rl) << 3;
    const int wq   = w * 1024;
    const int kq   = (lane >> 4) << 4;
    const int frx  = (fr & 7) << 4;

    constexpr int NT = N / 64;
    for (int kt = 0; kt < NT; ++kt) {
        const int k0s = kt * 64;
        {
            char* lb0 = (char*)sm + wq;
            #pragma unroll
            for (int q = 0; q < 2; ++q) {
                const int row = q * 32 + w * 8 + rl;
                const size_t xo = (size_t)(i0 + row) * N + k0s + gcol;
                const size_t yo = (size_t)(j0 + row) * N + k0s + gcol;
                GLDS16(Xh + xo, lb0 + q * 4096);
                GLDS16(Xl + xo, lb0 + 8192 + q * 4096);
                GLDS16(Yh + yo, lb0 + 16384 + q * 4096);
                GLDS16(Yl + yo, lb0 + 24576 + q * 4096);
            }
        }
        __syncthreads();
        {
            const char* base = (const char*)sm;
            #pragma unroll
            for (int s = 0; s < 2; ++s) {
                const int cb = s * 64 + kq;
                bfx8 ah[2], al[2];
                #pragma unroll
                for (int m = 0; m < 2; ++m) {
                    const int off = (wm + m * 16 + fr) * 128 + (cb ^ frx);
                    ah[m] = *(const bfx8*)(base + off);
                    al[m] = *(const bfx8*)(base + 8192 + off);
                }
                #pragma unroll
                for (int n = 0; n < 2; ++n) {
                    const int off = (wn + n * 16 + fr) * 128 + (cb ^ frx);
                    bfx8 bh = *(const bfx8*)(base + 16384 + off);
                    bfx8 bl = *(const bfx8*)(base + 24576 + off);
                    #pragma unroll
                    for (int m = 0; m < 2; ++m) {
                        acc[m][n] = __builtin_amdgcn_mfma_f32_16x16x32_bf16(ah[m], bh, acc[m][n], 0, 0, 0);
                        acc[m][n] = __builtin_amdgcn_mfma_f32_16x16x32_bf16(ah[m], bl, acc[m][n], 0, 0, 0);
                        acc[m][n] = __builtin_amdgcn_mfma_f32_16x16x32_bf16(al[m], bh, acc[m][n], 0, 0, 0);
                    }
                }
            }
        }
        __syncthreads();
    }

    // ---- epilogue 1: direct stores of the (by,bx) tile + stage in Ct ----
    float* Ct = (float*)sm;                         // [64][65] fp32 (16.6 KB)
    const int crow0 = (lane >> 4) * 4;
    #pragma unroll
    for (int m = 0; m < 2; ++m) {
        #pragma unroll
        for (int n = 0; n < 2; ++n) {
            #pragma unroll
            for (int r = 0; r < 4; ++r) {
                const int li = wm + m * 16 + crow0 + r;
                const int lj = wn + n * 16 + fr;
                float v = acc[m][n][r];
                if (MASKED) {
                    if (i0 + li != j0 + lj) v *= rowf[li] * colf[lj];
                }
                Ct[li * 65 + lj] = v;
                const size_t off = (size_t)(i0 + li) * N + j0 + lj;
                if (OMODE == 0) {
                    Cf[off] = v;
                } else {
                    u16 h = bf16_rne(v);
                    Cs[off]      = h;
                    Cs[NN + off] = bf16_rne(v - bf16_f(h));
                }
            }
        }
    }

    // ---- epilogue 2: mirror (bx,by) tile via transpose-read of Ct ----
    if (by != bx) {
        __syncthreads();
        const int rr  = tid >> 2;                   // mirror row j0+rr (0..63)
        const int cc0 = (tid & 3) * 16;             // mirror cols i0+cc0..+15
        float v[16];
        #pragma unroll
        for (int e = 0; e < 16; ++e) v[e] = Ct[(cc0 + e) * 65 + rr];
        const size_t off = (size_t)(j0 + rr) * N + i0 + cc0;
        if (OMODE == 0) {
            #pragma unroll
            for (int q = 0; q < 4; ++q)
                *(float4*)(Cf + off + q * 4) =
                    make_float4(v[q*4], v[q*4+1], v[q*4+2], v[q*4+3]);
        } else {
            bfx8 hs[2], ls[2];
            #pragma unroll
            for (int e = 0; e < 16; ++e) {
                u16 h = bf16_rne(v[e]);
                hs[e >> 3][e & 7] = (short)h;
                ls[e >> 3][e & 7] = (short)bf16_rne(v[e] - bf16_f(h));
            }
            *(bfx8*)(Cs + off)          = hs[0];
            *(bfx8*)(Cs + off + 8)      = hs[1];
            *(bfx8*)(Cs + NN + off)     = ls[0];
            *(bfx8*)(Cs + NN + off + 8) = ls[1];
        }
    }
}

// ---------------------------------------------------------------------------
// Schedule (park-free slot plan):
//   slots: O1=Arec, O2=R, O3=D (d_out); W1=ws[0:16M), W2=ws[16M:32M)
//   0. flags -> O1[0:256] (ints; overwritten later by R2)
//   1. front: RT -> O3, RT2 -> W1u, A2 = split(A) -> W2u   [fused launch]
//   2. split_rt: R2 -> O1u, R fp32 -> O2
//   3. G1: Ts  = split(R2 ⊛ A2^T)    -> O3u   [RT dead]   (128x64, grid 512)
//   4. G2: D2  = split(mask(Ts ⊛ R2^T)) -> W2u [A2 dead]  (SYM 64x64, 528)
//   5. G3: T2s = split(RT2 ⊛ D2^T)   -> O3u   [Ts dead]   (128x64, grid 512)
//   6. G4: Arec = T2s ⊛ RT2^T        -> O1 fp32 [R2 dead] (SYM 64x64, 528)
//   7. unsplit: D fp32 = D2(W2u)     -> O3    [T2s, RT2 dead]
// ws requirement: 32 MB. No d2d copies.
// ---------------------------------------------------------------------------
extern "C" void kernel_launch(void* const* d_in, const int* in_sizes, int n_in,
                              void* d_out, int out_size, void* d_ws, size_t ws_size,
                              hipStream_t stream) {
    const float* A     = (const float*)d_in[0];
    const float* O_all = (const float*)d_in[1];
    const int*   sel   = (const int*)d_in[2];
    const int*   wav   = (const int*)d_in[3];
    const int    Lw    = in_sizes[3];

    float* O1 = (float*)d_out;          // Arec slot
    float* O2 = O1 + NN;                // R slot
    float* O3 = O1 + 2 * NN;            // D slot

    u16*   W1u = (u16*)d_ws;                                  // ws[0,16M)
    u16*   W2u = (u16*)((char*)d_ws + 2 * NN * sizeof(u16));  // ws[16M,32M)
    u16*   O1u = (u16*)O1;
    u16*   O3u = (u16*)O3;
    int*   flg = (int*)O1;              // 1 KB; dead before split_rt writes R2

    const int SGRID = (int)(NN / (256 * 8));

    flags_k<<<1, 256, 0, stream>>>(sel, flg);
    front_k<<<2048 + (int)(NN / (64 * 8)), 64, 0, stream>>>(O_all, sel, flg, O3, W1u, A, W2u);
    split_rt_k<<<(N / 64) * (N / 64), 256, 0, stream>>>(O3, O1u, O2);

    gemm_bf3<0, 1><<<512, 256, 0, stream>>>(O1u, W2u, nullptr, O3u, nullptr, 0); // G1: Ts  -> O3u
    gemm_sym<1, 1><<<528, 256, 0, stream>>>(O3u, O1u, nullptr, W2u, wav, Lw);    // G2: D2  -> W2u (sym)
    gemm_bf3<0, 1><<<512, 256, 0, stream>>>(W1u, W2u, nullptr, O3u, nullptr, 0); // G3: T2s -> O3u
    gemm_sym<0, 0><<<528, 256, 0, stream>>>(O3u, W1u, O1, nullptr, nullptr, 0);  // G4: Arec -> O1 (sym)
    unsplit_k<<<SGRID, 256, 0, stream>>>(W2u, O3);                               // D fp32 -> O3
}

// Round 19
// 241.194 us; speedup vs baseline: 1.1527x; 1.1527x over previous
//
#include <hip/hip_runtime.h>

#define N 2048
#define LEV 256
#define KS 16

typedef __attribute__((ext_vector_type(8))) short bfx8;
typedef __attribute__((ext_vector_type(4))) float fx4;
typedef unsigned short u16;
typedef unsigned int u32;

static const size_t NN = (size_t)N * N;

__device__ inline u16 bf16_rne(float f) {
    u32 u = __builtin_bit_cast(u32, f);
    u32 r = (u + 0x7FFFu + ((u >> 16) & 1u)) >> 16;
    return (u16)r;
}
__device__ inline float bf16_f(u16 h) {
    u32 u = ((u32)h) << 16;
    return __builtin_bit_cast(float, u);
}

// async global->LDS, 16B per lane. LDS dest = wave-uniform base + lane*16.
#define GLDS16(gp, lp) __builtin_amdgcn_global_load_lds( \
    (const __attribute__((address_space(1))) void*)(uintptr_t)(gp), \
    (__attribute__((address_space(3))) void*)(u32)(uintptr_t)(lp), 16, 0, 0)

// sum over the 4 lanes of each quad (lane^1 then lane^2), VALU-only via DPP.
__device__ inline float qadd(float x) {
#if __has_builtin(__builtin_amdgcn_mov_dpp)
    int a = __builtin_amdgcn_mov_dpp(__builtin_bit_cast(int, x), 0xB1, 0xF, 0xF, true);
    float y = x + __builtin_bit_cast(float, a);
    int b = __builtin_amdgcn_mov_dpp(__builtin_bit_cast(int, y), 0x4E, 0xF, 0xF, true);
    return y + __builtin_bit_cast(float, b);
#else
    float y = x + __shfl_xor(x, 1);
    return y + __shfl_xor(y, 2);
#endif
}

// ---------------------------------------------------------------------------
// FUSED front: blocks [0,2048) build RT column (one col/wave, 2-deep
// prefetch; ~630cy/level chain floor — 5 structural attempts confirm) and
// emit ONLY RT2 split planes (RT fp32 dropped; split_rt reconstructs hi+lo).
// Blocks [2048,2048+8192) stream-split A into bf16 hi/lo planes.
// ---------------------------------------------------------------------------
__global__ __launch_bounds__(64)
void front_k(const float* __restrict__ O_all, const int* __restrict__ sel,
             u16* __restrict__ rth,
             const float* __restrict__ A, u16* __restrict__ a2h) {
    __shared__ float x[2048];
    const int lane = threadIdx.x;

    if (blockIdx.x >= 2048) {           // ---- A-split path ----
        u16* a2l = a2h + NN;
        size_t p = (((size_t)blockIdx.x - 2048) * 64 + lane) * 8;
        float4 v0 = *(const float4*)(A + p);
        float4 v1 = *(const float4*)(A + p + 4);
        float vv[8] = {v0.x, v0.y, v0.z, v0.w, v1.x, v1.y, v1.z, v1.w};
        bfx8 hs, ls;
        #pragma unroll
        for (int i = 0; i < 8; ++i) {
            u16 h = bf16_rne(vv[i]);
            hs[i] = (short)h;
            ls[i] = (short)bf16_rne(vv[i] - bf16_f(h));
        }
        *(bfx8*)(a2h + p) = hs;
        *(bfx8*)(a2l + p) = ls;
        return;
    }

    // ---- build-right path ----
    const int i    = lane >> 2;     // row 0..15
    const int kg   = lane & 3;      // k-quarter 0..3
    const int col  = blockIdx.x;

    const float4 z = make_float4(0.f, 0.f, 0.f, 0.f);
    #pragma unroll
    for (int q = 0; q < 8; ++q) *(float4*)&x[q * 256 + lane * 4] = z;
    if (lane == 0) x[col] = 1.0f;   // e_col; in-order DS, same wave

    const float* obase = O_all + i * KS + kg * 4;
    const int*   gbase = sel + kg * 4;

#define CMP(f, g, wv) { \
    float p = f.x * x[g.x] + f.y * x[g.y] + f.z * x[g.z] + f.w * x[g.w]; \
    p = qadd(p); \
    if (kg == 0) x[wv] = p; }

    float4 f0 = *(const float4*)(obase);
    int4   g0 = *(const int4*)(gbase);
    int    w0 = sel[i];
    float4 f1 = *(const float4*)(obase + 256);
    int4   g1 = *(const int4*)(gbase + KS);
    int    w1 = sel[KS + i];

    for (int l = 0; l < LEV; l += 2) {
        float4 f2, f3; int4 g2, g3; int w2, w3;
        if (l + 2 < LEV) {
            f2 = *(const float4*)(obase + (size_t)(l + 2) * 256);
            g2 = *(const int4*)(gbase + (l + 2) * KS);
            w2 = sel[(l + 2) * KS + i];
            f3 = *(const float4*)(obase + (size_t)(l + 3) * 256);
            g3 = *(const int4*)(gbase + (l + 3) * KS);
            w3 = sel[(l + 3) * KS + i];
        } else { f2 = f0; g2 = g0; w2 = w0; f3 = f1; g3 = g1; w3 = w1; }

        CMP(f0, g0, w0)
        CMP(f1, g1, w1)
        f0 = f2; g0 = g2; w0 = w2;
        f1 = f3; g1 = g3; w1 = w3;
    }
#undef CMP

    u16* rtl = rth + NN;
    #pragma unroll
    for (int q = 0; q < 8; ++q) {
        float4 v = *(const float4*)&x[q * 256 + lane * 4];
        float vv[4] = {v.x, v.y, v.z, v.w};
        u16 hh[4], ll[4];
        #pragma unroll
        for (int e = 0; e < 4; ++e) {
            hh[e] = bf16_rne(vv[e]);
            ll[e] = bf16_rne(vv[e] - bf16_f(hh[e]));
        }
        const size_t po = (size_t)col * N + q * 256 + lane * 4;
        *(ushort4*)(rth + po) = make_ushort4(hh[0], hh[1], hh[2], hh[3]);
        *(ushort4*)(rtl + po) = make_ushort4(ll[0], ll[1], ll[2], ll[3]);
    }
}

// ---------------------------------------------------------------------------
// From RT2 planes (hi/lo of R^T, row-major): reconstruct v = hi+lo, then
// emit R2 = split(R) planes + Rrm (R fp32, output slot) via 64x64 LDS
// transpose tiles. Reconstruction error <= 2^-17 relative (irrelevant vs
// the 0.4575 output threshold).
// ---------------------------------------------------------------------------
__global__ __launch_bounds__(256)
void split_rt_k(const u16* __restrict__ rth, u16* __restrict__ r2h,
                float* __restrict__ Rrm) {
    __shared__ float t[64][65];
    const u16* rtl = rth + NN;
    u16* r2l = r2h + NN;
    const int r0 = (blockIdx.x >> 5) * 64, c0 = (blockIdx.x & 31) * 64;
    #pragma unroll
    for (int i = 0; i < 16; ++i) {
        int q = i * 256 + threadIdx.x;
        int rr = q >> 6, cc = q & 63;
        const size_t po = (size_t)(r0 + rr) * N + c0 + cc;
        t[rr][cc] = bf16_f(rth[po]) + bf16_f(rtl[po]);
    }
    __syncthreads();
    #pragma unroll
    for (int i = 0; i < 16; ++i) {
        int q = i * 256 + threadIdx.x;
        int rr = q >> 6, cc = q & 63;
        float w = t[cc][rr];                        // = R[c0+rr][r0+cc]
        u16 h2 = bf16_rne(w);
        size_t pt = (size_t)(c0 + rr) * N + r0 + cc;
        r2h[pt] = h2;                               // split(R)
        r2l[pt] = bf16_rne(w - bf16_f(h2));
        Rrm[pt] = w;                                // R fp32 (output slot)
    }
}

// ---------------------------------------------------------------------------
// D fp32 = hi + lo
// ---------------------------------------------------------------------------
__global__ __launch_bounds__(256)
void unsplit_k(const u16* __restrict__ hi, float* __restrict__ dst) {
    const u16* lo = hi + NN;
    size_t p = ((size_t)blockIdx.x * 256 + threadIdx.x) * 8;
    bfx8 hs = *(const bfx8*)(hi + p);
    bfx8 ls = *(const bfx8*)(lo + p);
    float4 o0, o1;
    o0.x = bf16_f((u16)hs[0]) + bf16_f((u16)ls[0]);
    o0.y = bf16_f((u16)hs[1]) + bf16_f((u16)ls[1]);
    o0.z = bf16_f((u16)hs[2]) + bf16_f((u16)ls[2]);
    o0.w = bf16_f((u16)hs[3]) + bf16_f((u16)ls[3]);
    o1.x = bf16_f((u16)hs[4]) + bf16_f((u16)ls[4]);
    o1.y = bf16_f((u16)hs[5]) + bf16_f((u16)ls[5]);
    o1.z = bf16_f((u16)hs[6]) + bf16_f((u16)ls[6]);
    o1.w = bf16_f((u16)hs[7]) + bf16_f((u16)ls[7]);
    *(float4*)(dst + p)     = o0;
    *(float4*)(dst + p + 4) = o1;
}

// ---------------------------------------------------------------------------
// C = X * Y^T via 3-term bf16 split MFMA. R13-PROVEN: 128x64 tile, BK=64,
// single-buffered X+Y LDS via global_load_lds (48 KB) -> grid 512 = 2
// blocks/CU co-resident. Both-sides XOR swizzle; XCD super-tile swizzle.
// ---------------------------------------------------------------------------
template<int MASKED, int OMODE>
__global__ __launch_bounds__(256)
void gemm_bf3(const u16* __restrict__ Xp, const u16* __restrict__ Yp,
              float* __restrict__ Cf, u16* __restrict__ Cs,
              const int* __restrict__ wav, int Lw) {
    // planes: Xh[128*64] @0, Xl @16384, Yh[64*64] @32768, Yl @40960 (bytes)
    __shared__ __align__(16) u16 sm[24576];        // 48 KB single buffer
    __shared__ float rowf[128], colf[64];

    const int tid = threadIdx.x;
    const int xcd = blockIdx.x & 7, idx = blockIdx.x >> 3;   // idx 0..63
    const int sup = 4 * xcd + (idx >> 4);                    // 0..31
    const int wi4 = idx & 15;
    const int by = (sup >> 3) * 4 + (wi4 >> 2);              // 0..15
    const int bx = (sup & 7) * 4 + (wi4 & 3);                // 0..31
    const int i0 = by * 128, j0 = bx * 64;
    const int lane = tid & 63, w = tid >> 6;
    const int wm = (w >> 1) * 64, wn = (w & 1) * 32;
    const int fr = lane & 15;

    if (MASKED) {
        if (tid < 128) rowf[tid] = 1.0f;
        if (tid >= 128 && tid < 192) colf[tid - 128] = 1.0f;
        __syncthreads();
        for (int t = tid; t < Lw; t += 256) {
            int wv = wav[t];
            int dr = wv - i0; if (0 <= dr && dr < 128) rowf[dr] = 0.0f;
            int dc = wv - j0; if (0 <= dc && dc < 64)  colf[dc] = 0.0f;
        }
    }

    fx4 acc[4][2];
    #pragma unroll
    for (int m = 0; m < 4; ++m)
        #pragma unroll
        for (int n = 0; n < 2; ++n)
            acc[m][n] = (fx4)0.0f;

    const u16* Xh = Xp; const u16* Xl = Xp + NN;
    const u16* Yh = Yp; const u16* Yl = Yp + NN;

    const int rl   = lane >> 3;
    const int gcol = ((lane & 7) ^ rl) << 3;
    const int wq   = w * 1024;

    #define STAGE(kt) { \
        const int k0s = (kt) * 64; \
        char* lb0 = (char*)sm + wq; \
        _Pragma("unroll") \
        for (int q = 0; q < 4; ++q) { \
            const int row = q * 32 + w * 8 + rl; \
            const size_t xo = (size_t)(i0 + row) * N + k0s + gcol; \
            GLDS16(Xh + xo, lb0 + q * 4096); \
            GLDS16(Xl + xo, lb0 + 16384 + q * 4096); \
        } \
        _Pragma("unroll") \
        for (int q = 0; q < 2; ++q) { \
            const int row = q * 32 + w * 8 + rl; \
            const size_t yo = (size_t)(j0 + row) * N + k0s + gcol; \
            GLDS16(Yh + yo, lb0 + 32768 + q * 4096); \
            GLDS16(Yl + yo, lb0 + 40960 + q * 4096); \
        } }

    const int kq  = (lane >> 4) << 4;
    const int frx = (fr & 7) << 4;

    #define COMPUTE() { \
        const char* base = (const char*)sm; \
        _Pragma("unroll") \
        for (int s = 0; s < 2; ++s) { \
            const int cb = s * 64 + kq; \
            bfx8 ah[4], al[4]; \
            _Pragma("unroll") \
            for (int m = 0; m < 4; ++m) { \
                const int off = (wm + m * 16 + fr) * 128 + (cb ^ frx); \
                ah[m] = *(const bfx8*)(base + off); \
                al[m] = *(const bfx8*)(base + 16384 + off); \
            } \
            _Pragma("unroll") \
            for (int n = 0; n < 2; ++n) { \
                const int off = (wn + n * 16 + fr) * 128 + (cb ^ frx); \
                bfx8 bh = *(const bfx8*)(base + 32768 + off); \
                bfx8 bl = *(const bfx8*)(base + 40960 + off); \
                _Pragma("unroll") \
                for (int m = 0; m < 4; ++m) { \
                    acc[m][n] = __builtin_amdgcn_mfma_f32_16x16x32_bf16(ah[m], bh, acc[m][n], 0, 0, 0); \
                    acc[m][n] = __builtin_amdgcn_mfma_f32_16x16x32_bf16(ah[m], bl, acc[m][n], 0, 0, 0); \
                    acc[m][n] = __builtin_amdgcn_mfma_f32_16x16x32_bf16(al[m], bh, acc[m][n], 0, 0, 0); \
                } \
            } \
        } }

    constexpr int NT = N / 64;
    for (int kt = 0; kt < NT; ++kt) {
        STAGE(kt)
        __syncthreads();
        COMPUTE()
        __syncthreads();
    }

    const int crow0 = (lane >> 4) * 4;
    #pragma unroll
    for (int m = 0; m < 4; ++m) {
        #pragma unroll
        for (int n = 0; n < 2; ++n) {
            #pragma unroll
            for (int r = 0; r < 4; ++r) {
                const int li = wm + m * 16 + crow0 + r;
                const int lj = wn + n * 16 + fr;
                float v = acc[m][n][r];
                if (MASKED) {
                    if (i0 + li != j0 + lj) v *= rowf[li] * colf[lj];
                }
                const size_t off = (size_t)(i0 + li) * N + j0 + lj;
                if (OMODE == 0) {
                    Cf[off] = v;
                } else {
                    u16 h = bf16_rne(v);
                    Cs[off]      = h;
                    Cs[NN + off] = bf16_rne(v - bf16_f(h));
                }
            }
        }
    }
    #undef STAGE
    #undef COMPUTE
}

// ---------------------------------------------------------------------------
// SYMMETRIC-output GEMM (R17-proven): 64x64 tiles, 528 upper-tri blocks
// (>= 2 blocks/CU — the co-residency threshold R8/R9 violated). Off-diag
// blocks mirror via LDS bounce; diag blocks self-contained. Single-writer.
// ---------------------------------------------------------------------------
template<int MASKED, int OMODE>
__global__ __launch_bounds__(256)
void gemm_sym(const u16* __restrict__ Xp, const u16* __restrict__ Yp,
              float* __restrict__ Cf, u16* __restrict__ Cs,
              const int* __restrict__ wav, int Lw) {
    // planes: Xh[64*64] @0, Xl @8192, Yh @16384, Yl @24576 (bytes)
    __shared__ __align__(16) u16 sm[16384];        // 32 KB; epilogue Ct reuse
    __shared__ float rowf[64], colf[64];

    const int tid = threadIdx.x;
    int swz = (blockIdx.x & 7) * 66 + (blockIdx.x >> 3);
    int t = swz, by = 0;
    #pragma unroll 1
    while (t >= 32 - by) { t -= 32 - by; ++by; }
    const int bx = by + t;                          // by <= bx < 32
    const int i0 = by * 64, j0 = bx * 64;
    const int lane = tid & 63, w = tid >> 6;
    const int wm = (w >> 1) * 32, wn = (w & 1) * 32;
    const int fr = lane & 15;

    if (MASKED) {
        if (tid < 64) rowf[tid] = 1.0f;
        if (tid >= 128 && tid < 192) colf[tid - 128] = 1.0f;
        __syncthreads();
        for (int t2 = tid; t2 < Lw; t2 += 256) {
            int wv = wav[t2];
            int dr = wv - i0; if (0 <= dr && dr < 64) rowf[dr] = 0.0f;
            int dc = wv - j0; if (0 <= dc && dc < 64) colf[dc] = 0.0f;
        }
    }

    fx4 acc[2][2];
    #pragma unroll
    for (int m = 0; m < 2; ++m)
        #pragma unroll
        for (int n = 0; n < 2; ++n)
            acc[m][n] = (fx4)0.0f;

    const u16* Xh = Xp; const u16* Xl = Xp + NN;
    const u16* Yh = Yp; const u16* Yl = Yp + NN;

    const int rl   = lane >> 3;
    const int gcol = ((lane & 7) ^ rl) << 3;
    const int wq   = w * 1024;
    const int kq   = (lane >> 4) << 4;
    const int frx  = (fr & 7) << 4;

    constexpr int NT = N / 64;
    for (int kt = 0; kt < NT; ++kt) {
        const int k0s = kt * 64;
        {
            char* lb0 = (char*)sm + wq;
            #pragma unroll
            for (int q = 0; q < 2; ++q) {
                const int row = q * 32 + w * 8 + rl;
                const size_t xo = (size_t)(i0 + row) * N + k0s + gcol;
                const size_t yo = (size_t)(j0 + row) * N + k0s + gcol;
                GLDS16(Xh + xo, lb0 + q * 4096);
                GLDS16(Xl + xo, lb0 + 8192 + q * 4096);
                GLDS16(Yh + yo, lb0 + 16384 + q * 4096);
                GLDS16(Yl + yo, lb0 + 24576 + q * 4096);
            }
        }
        __syncthreads();
        {
            const char* base = (const char*)sm;
            #pragma unroll
            for (int s = 0; s < 2; ++s) {
                const int cb = s * 64 + kq;
                bfx8 ah[2], al[2];
                #pragma unroll
                for (int m = 0; m < 2; ++m) {
                    const int off = (wm + m * 16 + fr) * 128 + (cb ^ frx);
                    ah[m] = *(const bfx8*)(base + off);
                    al[m] = *(const bfx8*)(base + 8192 + off);
                }
                #pragma unroll
                for (int n = 0; n < 2; ++n) {
                    const int off = (wn + n * 16 + fr) * 128 + (cb ^ frx);
                    bfx8 bh = *(const bfx8*)(base + 16384 + off);
                    bfx8 bl = *(const bfx8*)(base + 24576 + off);
                    #pragma unroll
                    for (int m = 0; m < 2; ++m) {
                        acc[m][n] = __builtin_amdgcn_mfma_f32_16x16x32_bf16(ah[m], bh, acc[m][n], 0, 0, 0);
                        acc[m][n] = __builtin_amdgcn_mfma_f32_16x16x32_bf16(ah[m], bl, acc[m][n], 0, 0, 0);
                        acc[m][n] = __builtin_amdgcn_mfma_f32_16x16x32_bf16(al[m], bh, acc[m][n], 0, 0, 0);
                    }
                }
            }
        }
        __syncthreads();
    }

    // ---- epilogue 1: direct stores of the (by,bx) tile + stage in Ct ----
    float* Ct = (float*)sm;                         // [64][65] fp32 (16.6 KB)
    const int crow0 = (lane >> 4) * 4;
    #pragma unroll
    for (int m = 0; m < 2; ++m) {
        #pragma unroll
        for (int n = 0; n < 2; ++n) {
            #pragma unroll
            for (int r = 0; r < 4; ++r) {
                const int li = wm + m * 16 + crow0 + r;
                const int lj = wn + n * 16 + fr;
                float v = acc[m][n][r];
                if (MASKED) {
                    if (i0 + li != j0 + lj) v *= rowf[li] * colf[lj];
                }
                Ct[li * 65 + lj] = v;
                const size_t off = (size_t)(i0 + li) * N + j0 + lj;
                if (OMODE == 0) {
                    Cf[off] = v;
                } else {
                    u16 h = bf16_rne(v);
                    Cs[off]      = h;
                    Cs[NN + off] = bf16_rne(v - bf16_f(h));
                }
            }
        }
    }

    // ---- epilogue 2: mirror (bx,by) tile via transpose-read of Ct ----
    if (by != bx) {
        __syncthreads();
        const int rr  = tid >> 2;                   // mirror row j0+rr (0..63)
        const int cc0 = (tid & 3) * 16;             // mirror cols i0+cc0..+15
        float v[16];
        #pragma unroll
        for (int e = 0; e < 16; ++e) v[e] = Ct[(cc0 + e) * 65 + rr];
        const size_t off = (size_t)(j0 + rr) * N + i0 + cc0;
        if (OMODE == 0) {
            #pragma unroll
            for (int q = 0; q < 4; ++q)
                *(float4*)(Cf + off + q * 4) =
                    make_float4(v[q*4], v[q*4+1], v[q*4+2], v[q*4+3]);
        } else {
            bfx8 hs[2], ls[2];
            #pragma unroll
            for (int e = 0; e < 16; ++e) {
                u16 h = bf16_rne(v[e]);
                hs[e >> 3][e & 7] = (short)h;
                ls[e >> 3][e & 7] = (short)bf16_rne(v[e] - bf16_f(h));
            }
            *(bfx8*)(Cs + off)          = hs[0];
            *(bfx8*)(Cs + off + 8)      = hs[1];
            *(bfx8*)(Cs + NN + off)     = ls[0];
            *(bfx8*)(Cs + NN + off + 8) = ls[1];
        }
    }
}

// ---------------------------------------------------------------------------
// Schedule (park-free slot plan):
//   slots: O1=Arec, O2=R, O3=D (d_out); W1=ws[0:16M), W2=ws[16M:32M)
//   1. front: RT2 -> W1u, A2 = split(A) -> W2u   [fused launch]
//   2. split_rt: R2 -> O1u, R fp32 -> O2   (reconstructs from RT2 planes)
//   3. G1: Ts  = split(R2 ⊛ A2^T)    -> O3u              (128x64, grid 512)
//   4. G2: D2  = split(mask(Ts ⊛ R2^T)) -> W2u [A2 dead] (SYM 64x64, 528)
//   5. G3: T2s = split(RT2 ⊛ D2^T)   -> O3u   [Ts dead]  (128x64, grid 512)
//   6. G4: Arec = T2s ⊛ RT2^T        -> O1 fp32 [R2 dead](SYM 64x64, 528)
//   7. unsplit: D fp32 = D2(W2u)     -> O3    [T2s, RT2 dead]
// ws requirement: 32 MB. No d2d copies.
// ---------------------------------------------------------------------------
extern "C" void kernel_launch(void* const* d_in, const int* in_sizes, int n_in,
                              void* d_out, int out_size, void* d_ws, size_t ws_size,
                              hipStream_t stream) {
    const float* A     = (const float*)d_in[0];
    const float* O_all = (const float*)d_in[1];
    const int*   sel   = (const int*)d_in[2];
    const int*   wav   = (const int*)d_in[3];
    const int    Lw    = in_sizes[3];

    float* O1 = (float*)d_out;          // Arec slot
    float* O2 = O1 + NN;                // R slot
    float* O3 = O1 + 2 * NN;            // D slot

    u16*   W1u = (u16*)d_ws;                                  // ws[0,16M)
    u16*   W2u = (u16*)((char*)d_ws + 2 * NN * sizeof(u16));  // ws[16M,32M)
    u16*   O1u = (u16*)O1;
    u16*   O3u = (u16*)O3;

    const int SGRID = (int)(NN / (256 * 8));

    front_k<<<2048 + (int)(NN / (64 * 8)), 64, 0, stream>>>(O_all, sel, W1u, A, W2u);
    split_rt_k<<<(N / 64) * (N / 64), 256, 0, stream>>>(W1u, O1u, O2);

    gemm_bf3<0, 1><<<512, 256, 0, stream>>>(O1u, W2u, nullptr, O3u, nullptr, 0); // G1: Ts  -> O3u
    gemm_sym<1, 1><<<528, 256, 0, stream>>>(O3u, O1u, nullptr, W2u, wav, Lw);    // G2: D2  -> W2u (sym)
    gemm_bf3<0, 1><<<512, 256, 0, stream>>>(W1u, W2u, nullptr, O3u, nullptr, 0); // G3: T2s -> O3u
    gemm_sym<0, 0><<<528, 256, 0, stream>>>(O3u, W1u, O1, nullptr, nullptr, 0);  // G4: Arec -> O1 (sym)
    unsplit_k<<<SGRID, 256, 0, stream>>>(W2u, O3);                               // D fp32 -> O3
}